// Round 1
// baseline (533.529 us; speedup 1.0000x reference)
//
#include <hip/hip_runtime.h>
#include <math.h>

#define Bq 2
#define Hq 128
#define Wq 256
#define Cq 64
#define NHEADq 2
#define Kq 9
#define HIDq 256
#define HDq 32
#define HWq (Hq * Wq)
#define NTOK (Bq * HWq)

__device__ inline float wave_reduce_sum(float v) {
    #pragma unroll
    for (int m = 1; m < 64; m <<= 1) v += __shfl_xor(v, m, 64);
    return v;
}

__device__ inline float gelu_exact(float x) {
    return 0.5f * x * (1.0f + erff(x * 0.70710678118654752440f));
}

// ---------------- Kernel A: LN1 + v/off(loc)/attn projections ----------------
__global__ __launch_bounds__(64) void k_ln1_proj(
    const float* __restrict__ x, const float* __restrict__ ref,
    const float* __restrict__ g1, const float* __restrict__ be1,
    const float* __restrict__ Woff, const float* __restrict__ boff,
    const float* __restrict__ Wa, const float* __restrict__ ba,
    const float* __restrict__ Wv, const float* __restrict__ bv,
    float* __restrict__ v_ws, float* __restrict__ loc_ws, float* __restrict__ attn_ws)
{
    const int token = blockIdx.x;
    const int tid = threadIdx.x;

    float xv = x[(size_t)token * 64 + tid];
    float m = wave_reduce_sum(xv) * (1.0f / 64.0f);
    float d = xv - m;
    float var = wave_reduce_sum(d * d) * (1.0f / 64.0f);
    float h = d * rsqrtf(var + 1e-5f) * g1[tid] + be1[tid];

    __shared__ float hs[64];
    __shared__ float logits[18];
    hs[tid] = h;
    __syncthreads();

    // v projection (64 -> 64), store channel-last image (b, n, y, x, cc)
    float acc = bv[tid];
    #pragma unroll
    for (int j = 0; j < 64; ++j) acc = fmaf(hs[j], Wv[j * 64 + tid], acc);
    const int n = tid >> 5, cc = tid & 31;
    const int b = token / HWq, pix = token - b * HWq;
    v_ws[((size_t)(b * 2 + n) * HWq + pix) * 32 + cc] = acc;

    // offsets -> absolute sample locations
    if (tid < 36) {
        float a = boff[tid];
        #pragma unroll
        for (int j = 0; j < 64; ++j) a = fmaf(hs[j], Woff[j * 36 + tid], a);
        const int k = (tid % 18) >> 1, dd = tid & 1;
        loc_ws[(size_t)token * 36 + tid] = ref[((size_t)token * 9 + k) * 2 + dd] + a;
    }

    // attention logits
    if (tid < 18) {
        float a = ba[tid];
        #pragma unroll
        for (int j = 0; j < 64; ++j) a = fmaf(hs[j], Wa[j * 18 + tid], a);
        logits[tid] = a;
    }
    __syncthreads();

    // softmax over K=9 per head (2 heads, threads 0..1)
    if (tid < 2) {
        float mx = -1e30f;
        #pragma unroll
        for (int k = 0; k < 9; ++k) mx = fmaxf(mx, logits[tid * 9 + k]);
        float e[9], s = 0.0f;
        #pragma unroll
        for (int k = 0; k < 9; ++k) { e[k] = expf(logits[tid * 9 + k] - mx); s += e[k]; }
        const float inv = 1.0f / s;
        #pragma unroll
        for (int k = 0; k < 9; ++k) attn_ws[(size_t)token * 18 + tid * 9 + k] = e[k] * inv;
    }
}

// ---------------- Kernel B: bilinear sample + attn weight + Wo + residual ----
__global__ __launch_bounds__(64) void k_samp_wo(
    const float* __restrict__ x, const float* __restrict__ v_ws,
    const float* __restrict__ loc_ws, const float* __restrict__ attn_ws,
    const float* __restrict__ Wo, const float* __restrict__ bo,
    float* __restrict__ x1 /* = d_out */)
{
    const int token = blockIdx.x;
    const int tid = threadIdx.x;
    const int b = token / HWq;

    __shared__ float loc_s[36];
    __shared__ float attn_s[18];
    __shared__ float sout[64];
    if (tid < 36) loc_s[tid] = loc_ws[(size_t)token * 36 + tid];
    if (tid < 18) attn_s[tid] = attn_ws[(size_t)token * 18 + tid];
    __syncthreads();

    const int n = tid >> 5, cc = tid & 31;
    const float* __restrict__ vimg = v_ws + (size_t)(b * 2 + n) * HWq * 32;

    float acc = 0.0f;
    #pragma unroll
    for (int k = 0; k < 9; ++k) {
        const float gx = loc_s[n * 18 + k * 2 + 0];
        const float gy = loc_s[n * 18 + k * 2 + 1];
        const float a  = attn_s[n * 9 + k];
        const float ix = (gx + 1.0f) * 128.0f - 0.5f;   // W*0.5 = 128
        const float iy = (gy + 1.0f) * 64.0f - 0.5f;    // H*0.5 = 64
        const float x0f = floorf(ix), y0f = floorf(iy);
        const float wx1 = ix - x0f, wy1 = iy - y0f;
        const int x0 = (int)x0f, y0 = (int)y0f;
        float s = 0.0f;
        if (x0 >= 0 && x0 < Wq && y0 >= 0 && y0 < Hq)
            s += (1.0f - wx1) * (1.0f - wy1) * vimg[((size_t)y0 * Wq + x0) * 32 + cc];
        if (x0 + 1 >= 0 && x0 + 1 < Wq && y0 >= 0 && y0 < Hq)
            s += wx1 * (1.0f - wy1) * vimg[((size_t)y0 * Wq + (x0 + 1)) * 32 + cc];
        if (x0 >= 0 && x0 < Wq && y0 + 1 >= 0 && y0 + 1 < Hq)
            s += (1.0f - wx1) * wy1 * vimg[((size_t)(y0 + 1) * Wq + x0) * 32 + cc];
        if (x0 + 1 >= 0 && x0 + 1 < Wq && y0 + 1 >= 0 && y0 + 1 < Hq)
            s += wx1 * wy1 * vimg[((size_t)(y0 + 1) * Wq + (x0 + 1)) * 32 + cc];
        acc = fmaf(a, s, acc);
    }
    sout[tid] = acc;
    __syncthreads();

    float o = bo[tid];
    #pragma unroll
    for (int j = 0; j < 64; ++j) o = fmaf(sout[j], Wo[j * 64 + tid], o);
    x1[(size_t)token * 64 + tid] = o + x[(size_t)token * 64 + tid];
}

// ---------------- Kernel C: LN2 + W1 + GELU -> y ----------------
__global__ __launch_bounds__(64) void k_ln2_ff1(
    const float* __restrict__ x1, const float* __restrict__ g2, const float* __restrict__ be2,
    const float* __restrict__ W1, const float* __restrict__ c1,
    float* __restrict__ y_ws)
{
    const int token = blockIdx.x;
    const int tid = threadIdx.x;

    float xv = x1[(size_t)token * 64 + tid];
    float m = wave_reduce_sum(xv) * (1.0f / 64.0f);
    float d = xv - m;
    float var = wave_reduce_sum(d * d) * (1.0f / 64.0f);
    float h = d * rsqrtf(var + 1e-5f) * g2[tid] + be2[tid];

    __shared__ float hs[64];
    hs[tid] = h;
    __syncthreads();

    #pragma unroll
    for (int i = 0; i < 4; ++i) {
        const int hid = tid + 64 * i;
        float a = c1[hid];
        #pragma unroll
        for (int j = 0; j < 64; ++j) a = fmaf(hs[j], W1[j * 256 + hid], a);
        y_ws[(size_t)token * 256 + hid] = gelu_exact(a);
    }
}

// ---------------- Kernel D: depthwise 3x3 + GELU + W2 + residual -------------
__global__ __launch_bounds__(64) void k_dw_ff2(
    const float* __restrict__ y_ws, const float* __restrict__ Wdw, const float* __restrict__ bdw,
    const float* __restrict__ W2, const float* __restrict__ c2,
    float* __restrict__ out /* holds x1, updated in place */)
{
    const int token = blockIdx.x;
    const int tid = threadIdx.x;
    const int b = token / HWq, pix = token - b * HWq;
    const int hh = pix >> 8;        // W = 256
    const int ww = pix & 255;

    __shared__ float zs[256];
    const float* __restrict__ ybase = y_ws + (size_t)b * HWq * 256;

    #pragma unroll
    for (int i = 0; i < 4; ++i) {
        const int ch = tid + 64 * i;
        float acc = bdw[ch];
        #pragma unroll
        for (int ky = 0; ky < 3; ++ky) {
            const int yy = hh + ky - 1;
            if (yy < 0 || yy >= Hq) continue;
            #pragma unroll
            for (int kx = 0; kx < 3; ++kx) {
                const int xx = (ww + kx - 1 + Wq) & (Wq - 1);  // circular in width
                acc = fmaf(Wdw[ch * 9 + ky * 3 + kx],
                           ybase[((size_t)yy * Wq + xx) * 256 + ch], acc);
            }
        }
        zs[ch] = gelu_exact(acc);
    }
    __syncthreads();

    float o = c2[tid];
    #pragma unroll
    for (int j = 0; j < 256; ++j) o = fmaf(zs[j], W2[j * 64 + tid], o);
    out[(size_t)token * 64 + tid] += o;
}

extern "C" void kernel_launch(void* const* d_in, const int* in_sizes, int n_in,
                              void* d_out, int out_size, void* d_ws, size_t ws_size,
                              hipStream_t stream) {
    const float* x    = (const float*)d_in[0];
    const float* ref  = (const float*)d_in[1];
    const float* g1   = (const float*)d_in[2];
    const float* be1  = (const float*)d_in[3];
    const float* g2   = (const float*)d_in[4];
    const float* be2  = (const float*)d_in[5];
    const float* Woff = (const float*)d_in[6];
    const float* boff = (const float*)d_in[7];
    const float* Wa   = (const float*)d_in[8];
    const float* ba   = (const float*)d_in[9];
    const float* Wv   = (const float*)d_in[10];
    const float* bv   = (const float*)d_in[11];
    const float* Wo   = (const float*)d_in[12];
    const float* bo   = (const float*)d_in[13];
    const float* W1   = (const float*)d_in[14];
    const float* c1   = (const float*)d_in[15];
    const float* Wdw  = (const float*)d_in[16];
    const float* bdw  = (const float*)d_in[17];
    const float* W2   = (const float*)d_in[18];
    const float* c2   = (const float*)d_in[19];

    float* out = (float*)d_out;

    // workspace layout (floats)
    float* ws = (float*)d_ws;
    float* v_ws    = ws;                                   // B*2*HW*32  = 4,194,304
    float* loc_ws  = v_ws  + (size_t)Bq * 2 * HWq * 32;    // NTOK*36    = 2,359,296
    float* attn_ws = loc_ws + (size_t)NTOK * 36;           // NTOK*18    = 1,179,648
    float* y_ws    = attn_ws + (size_t)NTOK * 18;          // NTOK*256   = 16,777,216

    dim3 grid(NTOK), block(64);
    hipLaunchKernelGGL(k_ln1_proj, grid, block, 0, stream,
                       x, ref, g1, be1, Woff, boff, Wa, ba, Wv, bv,
                       v_ws, loc_ws, attn_ws);
    hipLaunchKernelGGL(k_samp_wo, grid, block, 0, stream,
                       x, v_ws, loc_ws, attn_ws, Wo, bo, out);
    hipLaunchKernelGGL(k_ln2_ff1, grid, block, 0, stream,
                       out, g2, be2, W1, c1, y_ws);
    hipLaunchKernelGGL(k_dw_ff2, grid, block, 0, stream,
                       y_ws, Wdw, bdw, W2, c2, out);
}